// Round 16
// baseline (255.715 us; speedup 1.0000x reference)
//
#include <hip/hip_runtime.h>
#include <hip/hip_bf16.h>

#define B_SZ 1024
#define C_SZ 100
#define D_SZ 768

#define BM 128                 // d-rows per block (M)
#define BN 256                 // b-cols per block (N)
#define BK 32                  // e per K-step
#define NKT (D_SZ / BK)        // 24
#define NTHREADS 512           // 8 waves: 2(M) x 4(N), wave tile 64x64
#define TPC 24                 // tiles/class: 6 M x 4 N

#define A_HALF (BM * BK)       // 4096 ushorts = 8 KB / buffer
#define X_HALF (BN * BK)       // 8192 ushorts = 16 KB / buffer

#define TBL_ELEMS ((size_t)C_SZ * D_SZ)          // 76,800
#define AP_ELEMS  ((size_t)C_SZ * D_SZ * D_SZ)   // 58,982,400
#define RB_ELEMS  ((size_t)B_SZ * D_SZ)          // 786,432

typedef float f32x4  __attribute__((ext_vector_type(4)));
typedef float f32x16 __attribute__((ext_vector_type(16)));
typedef short short8 __attribute__((ext_vector_type(8)));

__device__ __forceinline__ ushort f2bf(float f) {
    union { __hip_bfloat16 b; ushort u; } cv; cv.b = __float2bfloat16(f); return cv.u;
}
__device__ __forceinline__ float bf2f(ushort u) {
    union { __hip_bfloat16 b; ushort us; } cv; cv.us = u; return __bfloat162float(cv.b);
}
__device__ __forceinline__ void gload_lds16(const void* g, void* l) {
    __builtin_amdgcn_global_load_lds((const __attribute__((address_space(1))) void*)g,
                                     (__attribute__((address_space(3))) void*)l, 16, 0, 0);
}

// ---- prepass 1: rd = 1/diag, md = mean*rd ----
__global__ __launch_bounds__(256) void make_tables(const float* __restrict__ mean,
                                                   const float* __restrict__ diag,
                                                   float* __restrict__ rd,
                                                   float* __restrict__ md) {
    const int i = ((int)blockIdx.x * 256 + (int)threadIdx.x) * 4;
    if (i < (int)TBL_ELEMS) {
        const f32x4 dv = *(const f32x4*)(diag + i);
        const f32x4 mv = *(const f32x4*)(mean + i);
        f32x4 r, m;
        r.x = 1.0f / dv.x; r.y = 1.0f / dv.y; r.z = 1.0f / dv.z; r.w = 1.0f / dv.w;
        m.x = mv.x * r.x;  m.y = mv.y * r.y;  m.z = mv.z * r.z;  m.w = mv.w * r.w;
        *(f32x4*)(rd + i) = r;
        *(f32x4*)(md + i) = m;
    }
}

// ---- prepass 2: rawbf = bf16(raw) ----
__global__ __launch_bounds__(256) void conv_rawbf(const float* __restrict__ raw,
                                                  ushort* __restrict__ rb) {
    const size_t i = (size_t)blockIdx.x * 256 + threadIdx.x;
    const f32x4 v0 = *(const f32x4*)(raw + i * 8);
    const f32x4 v1 = *(const f32x4*)(raw + i * 8 + 4);
    short8 p;
    p[0]=(short)f2bf(v0.x); p[1]=(short)f2bf(v0.y); p[2]=(short)f2bf(v0.z); p[3]=(short)f2bf(v0.w);
    p[4]=(short)f2bf(v1.x); p[5]=(short)f2bf(v1.y); p[6]=(short)f2bf(v1.z); p[7]=(short)f2bf(v1.w);
    *(short8*)(rb + i * 8) = p;
}

// ---- prepass 3: A'[c][d][e] = bf16(A*rd_c[e]); w[c][d] = dot(A_row, md_c) ----
__global__ __launch_bounds__(512) void conv_aprime(const float* __restrict__ inv,
                                                   const float* __restrict__ rd,
                                                   const float* __restrict__ md,
                                                   ushort* __restrict__ ap,
                                                   float* __restrict__ w) {
    const int lane = (int)threadIdx.x & 63;
    const int wv   = (int)threadIdx.x >> 6;
    const int ridx = (int)blockIdx.x * 8 + wv;            // c*768+d
    const int c    = ridx / D_SZ;
    const float* arow = inv + (size_t)ridx * D_SZ;
    const float* rdc  = rd + (size_t)c * D_SZ;
    const float* mdc  = md + (size_t)c * D_SZ;
    ushort* aprow = ap + (size_t)ridx * D_SZ;
    float dot = 0.f;
    #pragma unroll
    for (int j = 0; j < 3; ++j) {
        const int e = j * 256 + lane * 4;
        const f32x4 a  = *(const f32x4*)(arow + e);
        const f32x4 r4 = *(const f32x4*)(rdc + e);
        const f32x4 m4 = *(const f32x4*)(mdc + e);
        dot += a.x * m4.x + a.y * m4.y + a.z * m4.z + a.w * m4.w;
        ushort4 p;
        p.x = f2bf(a.x * r4.x); p.y = f2bf(a.y * r4.y);
        p.z = f2bf(a.z * r4.z); p.w = f2bf(a.w * r4.w);
        *(ushort4*)(aprow + e) = p;
    }
    #pragma unroll
    for (int k = 1; k < 64; k <<= 1) dot += __shfl_xor(dot, k);
    if (lane == 0) w[ridx] = dot;
}

// MODE 2: A'/rawbf via gload_lds; fold: out += sum_d x[b,d]*(w[d]-t[d,b])
// R13 structure (best measured: 192us main, occ 38.5, FETCH 150MB) with
// MFMA 32x32x16: same LDS reads (8 b128/step/wave), same acc=64 f32/lane,
// but 8 MFMA instrs/step instead of 16 (64.6 vs 77.6 matrix-pipe cyc).
// __launch_bounds__(512,4) LOAD-BEARING (R12/R13: occ 21->38.5 = 280->192us).
// MODE 0: no-ws fallback (f32 sources, divides; w=0 pure -dist form)
template <int MODE>
__global__ __launch_bounds__(NTHREADS, 4) void fecam_scores(
        const float* __restrict__ raw, const float* __restrict__ mean,
        const float* __restrict__ diag, const float* __restrict__ inv,
        const float* __restrict__ rdT, const float* __restrict__ mdT,
        const float* __restrict__ wT,
        const ushort* __restrict__ apAll, const ushort* __restrict__ rbAll,
        float* __restrict__ out) {
    __shared__ __align__(16) ushort aLds[2 * A_HALF];   // 16 KB
    __shared__ __align__(16) ushort xLds[2 * X_HALF];   // 32 KB
    __shared__ float red[8 * 64];                       //  2 KB  -> 50 KB total

    const int tid = (int)threadIdx.x;
    const int bx  = (int)blockIdx.x;

    // XCD-pinned class grouping (validated R3); 4 N-sharers per A' panel
    const int x = bx & 7;
    const int slot0 = bx >> 3;
    const int nCls  = (x < 4) ? 13 : 12;
    const int baseC = (x < 4) ? x * 13 : 52 + (x - 4) * 12;
    const int ci = slot0 / TPC;
    if (ci >= nCls) return;
    const int t  = slot0 % TPC;
    const int c  = baseC + ci;
    const int d0 = (t >> 2) * BM;
    const int b0 = (t & 3) * BN;

    const int lane = tid & 63;
    const int wid  = tid >> 6;
    const int wm   = wid >> 2;      // 0..1 (M)
    const int wn   = wid & 3;       // 0..3 (N)
    const int l31  = lane & 31;
    const int l5   = lane >> 5;     // 0..1

    const ushort* apc = apAll + (size_t)c * D_SZ * D_SZ;
    const float*  Af  = inv + (size_t)c * D_SZ * D_SZ;

    // staging: source-side XOR swizzle q = (s&3) ^ ((r>>1)&3); LDS dest linear.
    // (R7/R13-validated: 0 bank conflicts)
    auto stage_a = [&](ushort* dst, int kt) {
        const int s = tid;                    // 512 slots: 128 rows x 4 chunks
        const int r = s >> 2;
        const int q = (s & 3) ^ ((r >> 1) & 3);
        if constexpr (MODE == 2) {
            gload_lds16(apc + (size_t)(d0 + r) * D_SZ + kt * BK + q * 8, dst + s * 8);
        } else {
            const float* gp = Af + (size_t)(d0 + r) * D_SZ + kt * BK + q * 8;
            const f32x4 a0 = *(const f32x4*)gp;
            const f32x4 a1 = *(const f32x4*)(gp + 4);
            short8 p;
            p[0]=(short)f2bf(a0.x); p[1]=(short)f2bf(a0.y); p[2]=(short)f2bf(a0.z); p[3]=(short)f2bf(a0.w);
            p[4]=(short)f2bf(a1.x); p[5]=(short)f2bf(a1.y); p[6]=(short)f2bf(a1.z); p[7]=(short)f2bf(a1.w);
            *(short8*)(dst + s * 8) = p;
        }
    };
    auto stage_x = [&](ushort* dst, int kt) {
        #pragma unroll
        for (int i = 0; i < 2; ++i) {
            const int s = tid + i * NTHREADS;  // 1024 slots: 256 rows x 4 chunks
            const int r = s >> 2;
            const int q = (s & 3) ^ ((r >> 1) & 3);
            const int e = kt * BK + q * 8;
            if constexpr (MODE == 2) {
                gload_lds16(rbAll + (size_t)(b0 + r) * D_SZ + e, dst + s * 8);
            } else {
                const float* rp = raw + (size_t)(b0 + r) * D_SZ + e;
                const f32x4 r0 = *(const f32x4*)rp, r1 = *(const f32x4*)(rp + 4);
                const f32x4 mm0 = *(const f32x4*)(mean + (size_t)c * D_SZ + e);
                const f32x4 mm1 = *(const f32x4*)(mean + (size_t)c * D_SZ + e + 4);
                const f32x4 gg0 = *(const f32x4*)(diag + (size_t)c * D_SZ + e);
                const f32x4 gg1 = *(const f32x4*)(diag + (size_t)c * D_SZ + e + 4);
                short8 p;
                p[0]=(short)f2bf((r0.x-mm0.x)/gg0.x); p[1]=(short)f2bf((r0.y-mm0.y)/gg0.y);
                p[2]=(short)f2bf((r0.z-mm0.z)/gg0.z); p[3]=(short)f2bf((r0.w-mm0.w)/gg0.w);
                p[4]=(short)f2bf((r1.x-mm1.x)/gg1.x); p[5]=(short)f2bf((r1.y-mm1.y)/gg1.y);
                p[6]=(short)f2bf((r1.z-mm1.z)/gg1.z); p[7]=(short)f2bf((r1.w-mm1.w)/gg1.w);
                *(short8*)(dst + s * 8) = p;
            }
        }
    };

    stage_a(aLds, 0);
    stage_x(xLds, 0);
    __syncthreads();

    f32x16 acc[2][2] = {};   // wave 64(M) x 64(N) as 2x2 of 32x32 frags

    // 32x32x16 A/B frag: row = l31, k-half = l5. chunk c0 = ks*2 + l5;
    // swizzled ch = c0 ^ ((row>>1)&3); row = base32 + l31 -> (l31>>1)&3.
    const int swz = (l31 >> 1) & 3;
    for (int kt = 0; kt < NKT; ++kt) {
        const int cur = kt & 1;
        if (kt + 1 < NKT) {
            stage_a(aLds + (cur ^ 1) * A_HALF, kt + 1);
            stage_x(xLds + (cur ^ 1) * X_HALF, kt + 1);
        }
        const ushort* ab = aLds + cur * A_HALF;
        const ushort* xb = xLds + cur * X_HALF;
        #pragma unroll
        for (int ks = 0; ks < 2; ++ks) {     // two K=16 slabs of the BK=32 step
            const int ch = (ks * 2 + l5) ^ swz;
            short8 xf[2], af[2];
            #pragma unroll
            for (int n = 0; n < 2; ++n)
                xf[n] = *(const short8*)(xb + ((wn * 64 + n * 32 + l31) * 4 + ch) * 8);
            #pragma unroll
            for (int m = 0; m < 2; ++m)
                af[m] = *(const short8*)(ab + ((wm * 64 + m * 32 + l31) * 4 + ch) * 8);
            __builtin_amdgcn_s_setprio(1);
            #pragma unroll
            for (int m = 0; m < 2; ++m)
                #pragma unroll
                for (int n = 0; n < 2; ++n)
                    acc[m][n] = __builtin_amdgcn_mfma_f32_32x32x16_bf16(af[m], xf[n], acc[m][n], 0, 0, 0);
            __builtin_amdgcn_s_setprio(0);
        }
        __syncthreads();
    }

    // ---- fold (R9-validated algebra): v = sum_d x[b,d]*(w[d]-t[d,b]) ----
    // 32x32 C/D layout (m74/m101): col(b) = l31, row(d) = (reg&3)+8*(reg>>2)+4*l5
    float v[2] = {};
    #pragma unroll
    for (int m = 0; m < 2; ++m) {
        #pragma unroll
        for (int j4 = 0; j4 < 4; ++j4) {    // reg group j4: rows 8*j4+4*l5+{0..3}
            const int dd = d0 + wm * 64 + m * 32 + 8 * j4 + 4 * l5;
            f32x4 rd4, md4, w4;
            if constexpr (MODE == 2) {
                rd4 = *(const f32x4*)(rdT + (size_t)c * D_SZ + dd);
                md4 = *(const f32x4*)(mdT + (size_t)c * D_SZ + dd);
                w4  = *(const f32x4*)(wT + (size_t)c * D_SZ + dd);
            } else {
                const f32x4 mm4 = *(const f32x4*)(mean + (size_t)c * D_SZ + dd);
                const f32x4 gg4 = *(const f32x4*)(diag + (size_t)c * D_SZ + dd);
                rd4.x = 1.0f/gg4.x; rd4.y = 1.0f/gg4.y; rd4.z = 1.0f/gg4.z; rd4.w = 1.0f/gg4.w;
                md4.x = mm4.x*rd4.x; md4.y = mm4.y*rd4.y; md4.z = mm4.z*rd4.z; md4.w = mm4.w*rd4.w;
                w4.x = 0.f; w4.y = 0.f; w4.z = 0.f; w4.w = 0.f;
            }
            #pragma unroll
            for (int n = 0; n < 2; ++n) {
                const int bl = b0 + wn * 64 + n * 32 + l31;
                const f32x4 rv = *(const f32x4*)(raw + (size_t)bl * D_SZ + dd);
                v[n] += (w4.x - acc[m][n][j4 * 4 + 0]) * (rv.x * rd4.x - md4.x)
                      + (w4.y - acc[m][n][j4 * 4 + 1]) * (rv.y * rd4.y - md4.y)
                      + (w4.z - acc[m][n][j4 * 4 + 2]) * (rv.z * rd4.z - md4.z)
                      + (w4.w - acc[m][n][j4 * 4 + 3]) * (rv.w * rd4.w - md4.w);
            }
        }
    }
    // reduce over the two l5 halves (same b-col, disjoint d-rows)
    #pragma unroll
    for (int n = 0; n < 2; ++n) v[n] += __shfl_xor(v[n], 32);
    if (lane < 32) {
        red[wid * 64 + l31]      = v[0];
        red[wid * 64 + 32 + l31] = v[1];
    }
    __syncthreads();
    if (tid < BN) {   // b-local = tid: wn = tid>>6, off = tid&63
        const int wno = tid >> 6;
        const int off = tid & 63;
        const float p = red[wno * 64 + off] + red[(4 + wno) * 64 + off];
        atomicAdd(out + (size_t)(b0 + tid) * C_SZ + c, p);
    }
}

extern "C" void kernel_launch(void* const* d_in, const int* in_sizes, int n_in,
                              void* d_out, int out_size, void* d_ws, size_t ws_size,
                              hipStream_t stream) {
    const float* raw  = (const float*)d_in[0];
    const float* mean = (const float*)d_in[1];
    const float* inv  = (const float*)d_in[2];
    const float* diag = (const float*)d_in[3];
    float* out = (float*)d_out;

    const size_t TBL_B = TBL_ELEMS * 4;                    // 307,200
    const size_t AP_B  = AP_ELEMS * 2;                     // 117,964,800
    const size_t RB_B  = RB_ELEMS * 2;                     //   1,572,864
    const size_t need  = 3 * TBL_B + AP_B + RB_B;          // ~120.5 MB

    hipMemsetAsync(d_out, 0, (size_t)out_size * sizeof(float), stream);
    dim3 grid(8 * 13 * TPC);                               // 2496

    if (ws_size >= need) {
        float*  rdT = (float*)d_ws;
        float*  mdT = (float*)((char*)d_ws + TBL_B);
        float*  wT  = (float*)((char*)d_ws + 2 * TBL_B);
        ushort* ap  = (ushort*)((char*)d_ws + 3 * TBL_B);
        ushort* rb  = (ushort*)((char*)d_ws + 3 * TBL_B + AP_B);
        make_tables<<<75, 256, 0, stream>>>(mean, diag, rdT, mdT);
        conv_rawbf<<<384, 256, 0, stream>>>(raw, rb);
        conv_aprime<<<9600, 512, 0, stream>>>(inv, rdT, mdT, ap, wT);
        fecam_scores<2><<<grid, NTHREADS, 0, stream>>>(raw, mean, diag, inv,
                                                       rdT, mdT, wT, ap, rb, out);
    } else {
        fecam_scores<0><<<grid, NTHREADS, 0, stream>>>(raw, mean, diag, inv,
                                                       nullptr, nullptr, nullptr,
                                                       nullptr, nullptr, out);
    }
}

// Round 17
// 236.293 us; speedup vs baseline: 1.0822x; 1.0822x over previous
//
#include <hip/hip_runtime.h>
#include <hip/hip_bf16.h>

#define B_SZ 1024
#define C_SZ 100
#define D_SZ 768

#define BM 128                 // d-rows per block (M)
#define BN 256                 // b-cols per block (N)
#define BK 32                  // e per K-step
#define NKT (D_SZ / BK)        // 24
#define NTHREADS 512           // 8 waves: 2(M) x 4(N), wave tile 64x64
#define TPC 24                 // tiles/class: 6 M x 4 N

#define A_HALF (BM * BK)       // 4096 ushorts = 8 KB / buffer
#define X_HALF (BN * BK)       // 8192 ushorts = 16 KB / buffer

#define TBL_ELEMS ((size_t)C_SZ * D_SZ)          // 76,800
#define AP_ELEMS  ((size_t)C_SZ * D_SZ * D_SZ)   // 58,982,400
#define RB_ELEMS  ((size_t)B_SZ * D_SZ)          // 786,432

typedef float f32x4 __attribute__((ext_vector_type(4)));
typedef short short8 __attribute__((ext_vector_type(8)));

__device__ __forceinline__ ushort f2bf(float f) {
    union { __hip_bfloat16 b; ushort u; } cv; cv.b = __float2bfloat16(f); return cv.u;
}
__device__ __forceinline__ float bf2f(ushort u) {
    union { __hip_bfloat16 b; ushort us; } cv; cv.us = u; return __bfloat162float(cv.b);
}
__device__ __forceinline__ void gload_lds16(const void* g, void* l) {
    __builtin_amdgcn_global_load_lds((const __attribute__((address_space(1))) void*)g,
                                     (__attribute__((address_space(3))) void*)l, 16, 0, 0);
}

// ---- prepass A (merged): blocks 0..74 build rd/md tables; 75..458 cast raw->bf16 ----
__global__ __launch_bounds__(256) void prep_small(const float* __restrict__ mean,
                                                  const float* __restrict__ diag,
                                                  const float* __restrict__ raw,
                                                  float* __restrict__ rd,
                                                  float* __restrict__ md,
                                                  ushort* __restrict__ rb) {
    const int bx = (int)blockIdx.x;
    if (bx < 75) {
        const int i = (bx * 256 + (int)threadIdx.x) * 4;
        if (i < (int)TBL_ELEMS) {
            const f32x4 dv = *(const f32x4*)(diag + i);
            const f32x4 mv = *(const f32x4*)(mean + i);
            f32x4 r, m;
            r.x = 1.0f / dv.x; r.y = 1.0f / dv.y; r.z = 1.0f / dv.z; r.w = 1.0f / dv.w;
            m.x = mv.x * r.x;  m.y = mv.y * r.y;  m.z = mv.z * r.z;  m.w = mv.w * r.w;
            *(f32x4*)(rd + i) = r;
            *(f32x4*)(md + i) = m;
        }
    } else {
        const size_t i = (size_t)(bx - 75) * 256 + threadIdx.x;   // 98304 chunks of 8
        const f32x4 v0 = *(const f32x4*)(raw + i * 8);
        const f32x4 v1 = *(const f32x4*)(raw + i * 8 + 4);
        short8 p;
        p[0]=(short)f2bf(v0.x); p[1]=(short)f2bf(v0.y); p[2]=(short)f2bf(v0.z); p[3]=(short)f2bf(v0.w);
        p[4]=(short)f2bf(v1.x); p[5]=(short)f2bf(v1.y); p[6]=(short)f2bf(v1.z); p[7]=(short)f2bf(v1.w);
        *(short8*)(rb + i * 8) = p;
    }
}

// ---- prepass B: A'[c][d][e] = bf16(A*rd_c[e]); w[c][d] = dot(A_row, md_c) ----
__global__ __launch_bounds__(512) void conv_aprime(const float* __restrict__ inv,
                                                   const float* __restrict__ rd,
                                                   const float* __restrict__ md,
                                                   ushort* __restrict__ ap,
                                                   float* __restrict__ w) {
    const int lane = (int)threadIdx.x & 63;
    const int wv   = (int)threadIdx.x >> 6;
    const int ridx = (int)blockIdx.x * 8 + wv;            // c*768+d
    const int c    = ridx / D_SZ;
    const float* arow = inv + (size_t)ridx * D_SZ;
    const float* rdc  = rd + (size_t)c * D_SZ;
    const float* mdc  = md + (size_t)c * D_SZ;
    ushort* aprow = ap + (size_t)ridx * D_SZ;
    float dot = 0.f;
    #pragma unroll
    for (int j = 0; j < 3; ++j) {
        const int e = j * 256 + lane * 4;
        const f32x4 a  = *(const f32x4*)(arow + e);
        const f32x4 r4 = *(const f32x4*)(rdc + e);
        const f32x4 m4 = *(const f32x4*)(mdc + e);
        dot += a.x * m4.x + a.y * m4.y + a.z * m4.z + a.w * m4.w;
        ushort4 p;
        p.x = f2bf(a.x * r4.x); p.y = f2bf(a.y * r4.y);
        p.z = f2bf(a.z * r4.z); p.w = f2bf(a.w * r4.w);
        *(ushort4*)(aprow + e) = p;
    }
    #pragma unroll
    for (int k = 1; k < 64; k <<= 1) dot += __shfl_xor(dot, k);
    if (lane == 0) w[ridx] = dot;
}

// MODE 2: A'/rawbf via gload_lds; fold: out += sum_d x[b,d]*(w[d]-t[d,b])
// == R13 measured best: main 192us, MfmaUtil 27%, occ 38.5%, FETCH 150MB,
// 0 bank conflicts, absmax 1.0. All 6 design-space neighbors measured worse
// (R8-R16). __launch_bounds__(512,4) LOAD-BEARING: occ 21->38.5 = 280->192us.
// MODE 0: no-ws fallback (f32 sources, divides; w=0 pure -dist form)
template <int MODE>
__global__ __launch_bounds__(NTHREADS, 4) void fecam_scores(
        const float* __restrict__ raw, const float* __restrict__ mean,
        const float* __restrict__ diag, const float* __restrict__ inv,
        const float* __restrict__ rdT, const float* __restrict__ mdT,
        const float* __restrict__ wT,
        const ushort* __restrict__ apAll, const ushort* __restrict__ rbAll,
        float* __restrict__ out) {
    __shared__ __align__(16) ushort aLds[2 * A_HALF];   // 16 KB
    __shared__ __align__(16) ushort xLds[2 * X_HALF];   // 32 KB
    __shared__ float red[8 * 64];                       //  2 KB  -> 50 KB total

    const int tid = (int)threadIdx.x;
    const int bx  = (int)blockIdx.x;

    // XCD-pinned class grouping (validated R3); 4 N-sharers per A' panel
    const int x = bx & 7;
    const int slot0 = bx >> 3;
    const int nCls  = (x < 4) ? 13 : 12;
    const int baseC = (x < 4) ? x * 13 : 52 + (x - 4) * 12;
    const int ci = slot0 / TPC;
    if (ci >= nCls) return;
    const int t  = slot0 % TPC;
    const int c  = baseC + ci;
    const int d0 = (t >> 2) * BM;
    const int b0 = (t & 3) * BN;

    const int lane = tid & 63;
    const int wid  = tid >> 6;
    const int wm   = wid >> 2;      // 0..1 (M)
    const int wn   = wid & 3;       // 0..3 (N)
    const int l15  = lane & 15;
    const int l4   = lane >> 4;

    const ushort* apc = apAll + (size_t)c * D_SZ * D_SZ;
    const float*  Af  = inv + (size_t)c * D_SZ * D_SZ;

    // staging: source-side XOR swizzle q = (s&3) ^ ((r>>1)&3); LDS dest linear.
    // (R7/R13-validated: 0 bank conflicts)
    auto stage_a = [&](ushort* dst, int kt) {
        const int s = tid;                    // 512 slots: 128 rows x 4 chunks
        const int r = s >> 2;
        const int q = (s & 3) ^ ((r >> 1) & 3);
        if constexpr (MODE == 2) {
            gload_lds16(apc + (size_t)(d0 + r) * D_SZ + kt * BK + q * 8, dst + s * 8);
        } else {
            const float* gp = Af + (size_t)(d0 + r) * D_SZ + kt * BK + q * 8;
            const f32x4 a0 = *(const f32x4*)gp;
            const f32x4 a1 = *(const f32x4*)(gp + 4);
            short8 p;
            p[0]=(short)f2bf(a0.x); p[1]=(short)f2bf(a0.y); p[2]=(short)f2bf(a0.z); p[3]=(short)f2bf(a0.w);
            p[4]=(short)f2bf(a1.x); p[5]=(short)f2bf(a1.y); p[6]=(short)f2bf(a1.z); p[7]=(short)f2bf(a1.w);
            *(short8*)(dst + s * 8) = p;
        }
    };
    auto stage_x = [&](ushort* dst, int kt) {
        #pragma unroll
        for (int i = 0; i < 2; ++i) {
            const int s = tid + i * NTHREADS;  // 1024 slots: 256 rows x 4 chunks
            const int r = s >> 2;
            const int q = (s & 3) ^ ((r >> 1) & 3);
            const int e = kt * BK + q * 8;
            if constexpr (MODE == 2) {
                gload_lds16(rbAll + (size_t)(b0 + r) * D_SZ + e, dst + s * 8);
            } else {
                const float* rp = raw + (size_t)(b0 + r) * D_SZ + e;
                const f32x4 r0 = *(const f32x4*)rp, r1 = *(const f32x4*)(rp + 4);
                const f32x4 mm0 = *(const f32x4*)(mean + (size_t)c * D_SZ + e);
                const f32x4 mm1 = *(const f32x4*)(mean + (size_t)c * D_SZ + e + 4);
                const f32x4 gg0 = *(const f32x4*)(diag + (size_t)c * D_SZ + e);
                const f32x4 gg1 = *(const f32x4*)(diag + (size_t)c * D_SZ + e + 4);
                short8 p;
                p[0]=(short)f2bf((r0.x-mm0.x)/gg0.x); p[1]=(short)f2bf((r0.y-mm0.y)/gg0.y);
                p[2]=(short)f2bf((r0.z-mm0.z)/gg0.z); p[3]=(short)f2bf((r0.w-mm0.w)/gg0.w);
                p[4]=(short)f2bf((r1.x-mm1.x)/gg1.x); p[5]=(short)f2bf((r1.y-mm1.y)/gg1.y);
                p[6]=(short)f2bf((r1.z-mm1.z)/gg1.z); p[7]=(short)f2bf((r1.w-mm1.w)/gg1.w);
                *(short8*)(dst + s * 8) = p;
            }
        }
    };

    stage_a(aLds, 0);
    stage_x(xLds, 0);
    __syncthreads();

    f32x4 acc[4][4] = {};   // wave 64(M) x 64(N)

    // frag chunk lane-constant: fch = l4 ^ ((l15>>1)&3)  (matches source swz)
    const int fch = l4 ^ ((l15 >> 1) & 3);
    for (int kt = 0; kt < NKT; ++kt) {
        const int cur = kt & 1;
        if (kt + 1 < NKT) {
            stage_a(aLds + (cur ^ 1) * A_HALF, kt + 1);
            stage_x(xLds + (cur ^ 1) * X_HALF, kt + 1);
        }
        const ushort* ab = aLds + cur * A_HALF;
        const ushort* xb = xLds + cur * X_HALF;
        short8 xf[4];
        #pragma unroll
        for (int n = 0; n < 4; ++n)
            xf[n] = *(const short8*)(xb + ((wn * 64 + n * 16 + l15) * 4 + fch) * 8);
        #pragma unroll
        for (int m = 0; m < 4; ++m) {
            const short8 af = *(const short8*)(ab + ((wm * 64 + m * 16 + l15) * 4 + fch) * 8);
            #pragma unroll
            for (int n = 0; n < 4; ++n)
                acc[m][n] = __builtin_amdgcn_mfma_f32_16x16x32_bf16(af, xf[n], acc[m][n], 0, 0, 0);
        }
        __syncthreads();
    }

    // ---- fold (R9-validated): v[n] = sum_d x[b,d]*(w[d]-t[d,b]), x in f32 ----
    // C/D layout (validated): col(b)=l15, row(d)=l4*4+j
    float v[4] = {};
    #pragma unroll
    for (int m = 0; m < 4; ++m) {
        const int dd = d0 + wm * 64 + m * 16 + l4 * 4;
        f32x4 rd4, md4, w4;
        if constexpr (MODE == 2) {
            rd4 = *(const f32x4*)(rdT + (size_t)c * D_SZ + dd);
            md4 = *(const f32x4*)(mdT + (size_t)c * D_SZ + dd);
            w4  = *(const f32x4*)(wT + (size_t)c * D_SZ + dd);
        } else {
            const f32x4 mm4 = *(const f32x4*)(mean + (size_t)c * D_SZ + dd);
            const f32x4 gg4 = *(const f32x4*)(diag + (size_t)c * D_SZ + dd);
            rd4.x = 1.0f/gg4.x; rd4.y = 1.0f/gg4.y; rd4.z = 1.0f/gg4.z; rd4.w = 1.0f/gg4.w;
            md4.x = mm4.x*rd4.x; md4.y = mm4.y*rd4.y; md4.z = mm4.z*rd4.z; md4.w = mm4.w*rd4.w;
            w4.x = 0.f; w4.y = 0.f; w4.z = 0.f; w4.w = 0.f;
        }
        #pragma unroll
        for (int n = 0; n < 4; ++n) {
            const int bl = b0 + wn * 64 + n * 16 + l15;
            const f32x4 rv = *(const f32x4*)(raw + (size_t)bl * D_SZ + dd);
            v[n] += (w4.x - acc[m][n][0]) * (rv.x * rd4.x - md4.x)
                  + (w4.y - acc[m][n][1]) * (rv.y * rd4.y - md4.y)
                  + (w4.z - acc[m][n][2]) * (rv.z * rd4.z - md4.z)
                  + (w4.w - acc[m][n][3]) * (rv.w * rd4.w - md4.w);
        }
    }
    #pragma unroll
    for (int n = 0; n < 4; ++n) {
        v[n] += __shfl_xor(v[n], 16);
        v[n] += __shfl_xor(v[n], 32);
    }
    if (lane < 16) {
        #pragma unroll
        for (int n = 0; n < 4; ++n) red[wid * 64 + n * 16 + l15] = v[n];
    }
    __syncthreads();
    if (tid < BN) {   // b-local = tid: wn = tid>>6, off = tid&63
        const int wno = tid >> 6;
        const int off = tid & 63;
        const float p = red[wno * 64 + off] + red[(4 + wno) * 64 + off];
        atomicAdd(out + (size_t)(b0 + tid) * C_SZ + c, p);
    }
}

extern "C" void kernel_launch(void* const* d_in, const int* in_sizes, int n_in,
                              void* d_out, int out_size, void* d_ws, size_t ws_size,
                              hipStream_t stream) {
    const float* raw  = (const float*)d_in[0];
    const float* mean = (const float*)d_in[1];
    const float* inv  = (const float*)d_in[2];
    const float* diag = (const float*)d_in[3];
    float* out = (float*)d_out;

    const size_t TBL_B = TBL_ELEMS * 4;                    // 307,200
    const size_t AP_B  = AP_ELEMS * 2;                     // 117,964,800
    const size_t RB_B  = RB_ELEMS * 2;                     //   1,572,864
    const size_t need  = 3 * TBL_B + AP_B + RB_B;          // ~120.5 MB

    hipMemsetAsync(d_out, 0, (size_t)out_size * sizeof(float), stream);
    dim3 grid(8 * 13 * TPC);                               // 2496

    if (ws_size >= need) {
        float*  rdT = (float*)d_ws;
        float*  mdT = (float*)((char*)d_ws + TBL_B);
        float*  wT  = (float*)((char*)d_ws + 2 * TBL_B);
        ushort* ap  = (ushort*)((char*)d_ws + 3 * TBL_B);
        ushort* rb  = (ushort*)((char*)d_ws + 3 * TBL_B + AP_B);
        prep_small<<<75 + 384, 256, 0, stream>>>(mean, diag, raw, rdT, mdT, rb);
        conv_aprime<<<9600, 512, 0, stream>>>(inv, rdT, mdT, ap, wT);
        fecam_scores<2><<<grid, NTHREADS, 0, stream>>>(raw, mean, diag, inv,
                                                       rdT, mdT, wT, ap, rb, out);
    } else {
        fecam_scores<0><<<grid, NTHREADS, 0, stream>>>(raw, mean, diag, inv,
                                                       nullptr, nullptr, nullptr,
                                                       nullptr, nullptr, out);
    }
}